// Round 7
// baseline (1529.038 us; speedup 1.0000x reference)
//
#include <hip/hip_runtime.h>
#include <hip/hip_bf16.h>
#include <stdint.h>

#define HFR 128
#define HTO 128
#define LDN 136   // wt stride in bf16 (16B aligned rows, conflict-free)
#define TM  64    // node tile
#define SE  68    // even/odd LDS stride in floats (2-way bank aliasing, 16B aligned)

typedef short short8 __attribute__((ext_vector_type(8)));   // 8 bf16 = 4 VGPRs
typedef float f32x4  __attribute__((ext_vector_type(4)));   // MFMA C/D
typedef unsigned long long u64;

static __device__ __forceinline__ unsigned short f2bf(float x) {
    __hip_bfloat16 h = __float2bfloat16(x);
    return *reinterpret_cast<unsigned short*>(&h);
}
static __device__ __forceinline__ float bflo(unsigned int x) {
    return __uint_as_float(x << 16);           // low bf16 -> f32
}
static __device__ __forceinline__ float bfhi(unsigned int x) {
    return __uint_as_float(x & 0xffff0000u);   // high bf16 -> f32
}

// ---------------------------------------------------------------------------
// prep: three block ranges.
//   [0, ZB)        : zero cnt[nseg] (int4 stores)
//   [ZB, ZB+CB)    : nodes fp32 -> bf16
//   [ZB+CB, +WB)   : weights fp32 -> bf16
// ---------------------------------------------------------------------------
__global__ __launch_bounds__(256)
void prep_kernel(const float* __restrict__ nodes, const float* __restrict__ weights,
                 int* __restrict__ cnt, unsigned short* __restrict__ nb,
                 unsigned short* __restrict__ wb,
                 int nseg, int nfeat, int nw, int ZB, int CB) {
    int b = blockIdx.x;
    if (b < ZB) {
        int i = (b * 256 + threadIdx.x) * 4;
        if (i < nseg) {                       // nseg % 4 == 0
            int4 z = make_int4(0, 0, 0, 0);
            *reinterpret_cast<int4*>(cnt + i) = z;
        }
        return;
    }
    const float* src; unsigned short* dst; int i, lim;
    if (b < ZB + CB) { src = nodes;   dst = nb; i = ((b - ZB) * 256 + threadIdx.x) * 8;      lim = nfeat; }
    else             { src = weights; dst = wb; i = ((b - ZB - CB) * 256 + threadIdx.x) * 8; lim = nw; }
    if (i < lim) {
        const float4* s = reinterpret_cast<const float4*>(src + i);
        float4 v0 = s[0], v1 = s[1];
        short8 sv;
        sv[0] = f2bf(v0.x); sv[1] = f2bf(v0.y); sv[2] = f2bf(v0.z); sv[3] = f2bf(v0.w);
        sv[4] = f2bf(v1.x); sv[5] = f2bf(v1.y); sv[6] = f2bf(v1.z); sv[7] = f2bf(v1.w);
        *reinterpret_cast<short8*>(dst + i) = sv;
    }
}

// ---------------------------------------------------------------------------
// histogram over full row ids (r*N + dst)
// ---------------------------------------------------------------------------
__global__ __launch_bounds__(256)
void count_kernel(const int* __restrict__ rows, int* __restrict__ cnt, int nnz) {
    int e = blockIdx.x * 256 + threadIdx.x;
    if (e < nnz) atomicAdd(&cnt[rows[e]], 1);
}

// ---------------------------------------------------------------------------
// hierarchical exclusive scan, 1024 elems per 256-thread block (int4).
// ---------------------------------------------------------------------------
__global__ __launch_bounds__(256)
void scan_reduce(const int* __restrict__ cnt, int* __restrict__ bsum, int n) {
    __shared__ int s[256];
    int t = threadIdx.x;
    int i = blockIdx.x * 1024 + t * 4;
    int v = 0;
    if (i + 3 < n) { int4 q = *reinterpret_cast<const int4*>(cnt + i); v = q.x + q.y + q.z + q.w; }
    else { for (int k = 0; k < 4; ++k) if (i + k < n) v += cnt[i + k]; }
    s[t] = v;
    __syncthreads();
    for (int off = 128; off > 0; off >>= 1) {
        if (t < off) s[t] += s[t + off];
        __syncthreads();
    }
    if (t == 0) bsum[blockIdx.x] = s[0];
}

__global__ __launch_bounds__(1024)
void scan_block(int* __restrict__ bsum, int nb) {
    __shared__ int s[1024];
    int t = threadIdx.x;
    s[t] = (t < nb) ? bsum[t] : 0;
    __syncthreads();
    for (int off = 1; off < 1024; off <<= 1) {
        int o = (t >= off) ? s[t - off] : 0;
        __syncthreads();
        s[t] += o;
        __syncthreads();
    }
    if (t < nb) bsum[t] = (t == 0) ? 0 : s[t - 1];
}

__global__ __launch_bounds__(256)
void scan_final(int* __restrict__ cnt, const int* __restrict__ bsum, int n) {
    __shared__ int s[256];
    int t = threadIdx.x;
    int i = blockIdx.x * 1024 + t * 4;
    int4 q = make_int4(0, 0, 0, 0);
    if (i + 3 < n) q = *reinterpret_cast<const int4*>(cnt + i);
    else {
        if (i     < n) q.x = cnt[i];
        if (i + 1 < n) q.y = cnt[i + 1];
        if (i + 2 < n) q.z = cnt[i + 2];
        if (i + 3 < n) q.w = cnt[i + 3];
    }
    int tot = q.x + q.y + q.z + q.w;
    s[t] = tot;
    __syncthreads();
    for (int off = 1; off < 256; off <<= 1) {
        int o = (t >= off) ? s[t - off] : 0;
        __syncthreads();
        s[t] += o;
        __syncthreads();
    }
    int ex = ((t == 0) ? 0 : s[t - 1]) + bsum[blockIdx.x];
    int4 w;
    w.x = ex; w.y = ex + q.x; w.z = w.y + q.y; w.w = w.z + q.z;
    if (i + 3 < n) *reinterpret_cast<int4*>(cnt + i) = w;
    else {
        if (i     < n) cnt[i]     = w.x;
        if (i + 1 < n) cnt[i + 1] = w.y;
        if (i + 2 < n) cnt[i + 2] = w.z;
        if (i + 3 < n) cnt[i + 3] = w.w;
    }
}

// ---------------------------------------------------------------------------
// place: counting-sort pass 2, key = full row id.
// Record = val(32) | dstin(6, bits 17..22) | col(17, bits 0..16).
// Post-pass: cnt[s] == end(s) == start(s+1).
// ---------------------------------------------------------------------------
__global__ __launch_bounds__(256)
void place_kernel(const int* __restrict__ rows, const int* __restrict__ cols,
                  const float* __restrict__ vals,
                  int* __restrict__ cnt, u64* __restrict__ sorted, int N, int nnz) {
    int e = blockIdx.x * 256 + threadIdx.x;
    if (e >= nnz) return;
    int row = rows[e];
    int r   = row / N;
    int dst = row - r * N;
    int pos = atomicAdd(&cnt[row], 1);
    unsigned int lo = (unsigned int)cols[e] | ((unsigned int)(dst & (TM - 1)) << 17);
    sorted[pos] = ((u64)__float_as_uint(vals[e]) << 32) | (u64)lo;
}

// ---------------------------------------------------------------------------
// FUSED aggregate+GEMM: one block per 64-node tile.
// Per r: zero fp32 LDS tile (even/odd feature arrays), stream the tile's
// contiguous edge range (all 4 waves, interleaved stride-4, 4-unrolled):
// gather bf16 node row (256B coalesced, L3-resident), ds_add_f32 into tile.
// Then 32 MFMA against W[r] staged in LDS; C accumulates across r in AGPRs.
// Epilogue: LDS round-trip, relu, coalesced float4 stores. No global
// intermediate — the [R,N,128] agg never exists.
// ---------------------------------------------------------------------------
__global__ __launch_bounds__(256, 2)
void fused_kernel(const u64* __restrict__ sorted, const int* __restrict__ cnt,
                  const unsigned short* __restrict__ nb,
                  const unsigned short* __restrict__ wb,
                  float* __restrict__ out, int N, int R) {
    __shared__ float evn[TM * SE];
    __shared__ float odd[TM * SE];
    __shared__ unsigned short wt[128 * LDN];

    const int t    = threadIdx.x;
    const int n0   = blockIdx.x * TM;
    const int lane = t & 63;
    const int w    = t >> 6;        // wave 0..3 -> rows w*16..w*16+15
    const int m    = lane & 15;
    const int quad = lane >> 4;
    const int q8   = quad * 8;

    f32x4 acc[8];
#pragma unroll
    for (int j = 0; j < 8; ++j) acc[j] = (f32x4)(0.f);

    const unsigned int* nbu = reinterpret_cast<const unsigned int*>(nb);

    for (int r = 0; r < R; ++r) {
        __syncthreads();   // prev r's MFMA reads of evn/odd/wt done
        // ---- zero the fp32 accumulation tile
        float4 z4 = make_float4(0.f, 0.f, 0.f, 0.f);
        for (int i = t; i < TM * SE / 4; i += 256) {
            reinterpret_cast<float4*>(evn)[i] = z4;
            reinterpret_cast<float4*>(odd)[i] = z4;
        }
        // ---- stage W[r]
        const unsigned short* wsrc = wb + (size_t)r * HFR * HTO;
#pragma unroll
        for (int it = 0; it < 8; ++it) {
            int id  = t + 256 * it;
            int row = id >> 4;
            int k8  = id & 15;
            *reinterpret_cast<short8*>(&wt[row * LDN + k8 * 8]) =
                *reinterpret_cast<const short8*>(wsrc + row * HFR + k8 * 8);
        }
        __syncthreads();

        // ---- edge accumulation: contiguous range for this (tile, r)
        const int s_lo = r * N + n0;
        const int hi_n = min(n0 + TM - 1, N - 1);
        const int E0   = (s_lo == 0) ? 0 : cnt[s_lo - 1];
        const int E1   = cnt[r * N + hi_n];

#define DECODE(q, x, vv, din)                                              \
        unsigned int x;                                                    \
        float vv; int din;                                                 \
        {                                                                  \
            unsigned int lo_ = (unsigned int)(q);                          \
            vv  = __uint_as_float((unsigned int)((q) >> 32));              \
            din = (int)((lo_ >> 17) & (TM - 1));                           \
            x   = nbu[(((size_t)(lo_ & 0x1FFFF)) << 6) + lane];            \
        }

        int e = E0 + w;
        for (; e + 12 < E1; e += 16) {
            u64 q0 = sorted[e], q1 = sorted[e + 4], q2 = sorted[e + 8], q3 = sorted[e + 12];
            DECODE(q0, x0, v0, d0)
            DECODE(q1, x1, v1, d1)
            DECODE(q2, x2, v2, d2)
            DECODE(q3, x3, v3, d3)
            atomicAdd(&evn[d0 * SE + lane], bflo(x0) * v0);
            atomicAdd(&odd[d0 * SE + lane], bfhi(x0) * v0);
            atomicAdd(&evn[d1 * SE + lane], bflo(x1) * v1);
            atomicAdd(&odd[d1 * SE + lane], bfhi(x1) * v1);
            atomicAdd(&evn[d2 * SE + lane], bflo(x2) * v2);
            atomicAdd(&odd[d2 * SE + lane], bfhi(x2) * v2);
            atomicAdd(&evn[d3 * SE + lane], bflo(x3) * v3);
            atomicAdd(&odd[d3 * SE + lane], bfhi(x3) * v3);
        }
        for (; e < E1; e += 4) {
            u64 q0 = sorted[e];
            DECODE(q0, x0, v0, d0)
            atomicAdd(&evn[d0 * SE + lane], bflo(x0) * v0);
            atomicAdd(&odd[d0 * SE + lane], bfhi(x0) * v0);
        }
#undef DECODE
        __syncthreads();

        // ---- MFMA: A row = tile row w*16 + m, features interleaved from evn/odd
#pragma unroll
        for (int kk = 0; kk < HFR; kk += 32) {
            int d0   = (kk + q8) >> 1;          // dword-pair index, 16B aligned
            int arow = w * 16 + m;
            float4 ef = *reinterpret_cast<const float4*>(&evn[arow * SE + d0]);
            float4 of = *reinterpret_cast<const float4*>(&odd[arow * SE + d0]);
            short8 a;
            a[0] = f2bf(ef.x); a[1] = f2bf(of.x);
            a[2] = f2bf(ef.y); a[3] = f2bf(of.y);
            a[4] = f2bf(ef.z); a[5] = f2bf(of.z);
            a[6] = f2bf(ef.w); a[7] = f2bf(of.w);
#pragma unroll
            for (int j = 0; j < 8; ++j) {
                short8 b = *reinterpret_cast<const short8*>(&wt[(j * 16 + m) * LDN + kk + q8]);
                acc[j] = __builtin_amdgcn_mfma_f32_16x16x32_bf16(a, b, acc[j], 0, 0, 0);
            }
        }
    }

    // ---- epilogue: AGPR -> LDS (reuse wt) -> coalesced relu'd float4 stores
    __syncthreads();
    float* lf = reinterpret_cast<float*>(wt);   // 64 x 132 floats = 33792B
#pragma unroll
    for (int reg = 0; reg < 4; ++reg) {
        int lr = w * 16 + quad * 4 + reg;
#pragma unroll
        for (int j = 0; j < 8; ++j)
            lf[lr * 132 + m + 16 * j] = acc[j][reg];
    }
    __syncthreads();
#pragma unroll
    for (int it = 0; it < 8; ++it) {
        int id  = t + 256 * it;        // 64 rows x 32 float4
        int row = id >> 5;
        int k4  = id & 31;
        int n = n0 + row;
        if (n < N) {
            float4 v = *reinterpret_cast<const float4*>(&lf[row * 132 + k4 * 4]);
            v.x = fmaxf(v.x, 0.f); v.y = fmaxf(v.y, 0.f);
            v.z = fmaxf(v.z, 0.f); v.w = fmaxf(v.w, 0.f);
            *reinterpret_cast<float4*>(out + (size_t)n * HTO + k4 * 4) = v;
        }
    }
}

// ---------------------------------------------------------------------------
extern "C" void kernel_launch(void* const* d_in, const int* in_sizes, int n_in,
                              void* d_out, int out_size, void* d_ws, size_t ws_size,
                              hipStream_t stream) {
    const float* nodes   = (const float*)d_in[0];   // [N, HFR] fp32
    const int*   indices = (const int*)d_in[1];     // [2, NNZ] int32
    const float* vals    = (const float*)d_in[2];   // [NNZ] fp32
    const float* weights = (const float*)d_in[3];   // [R, HFR, HTO] fp32

    const int N    = in_sizes[0] / HFR;
    const int nnz  = in_sizes[1] / 2;
    const int R    = in_sizes[3] / (HFR * HTO);
    const int nseg = N * R;

    const int* rows = indices;
    const int* cols = indices + nnz;

    // ws layout (~42 MB):
    //   nb     : [N*128] bf16      (25.6 MB)
    //   sorted : [nnz] u64         (12.8 MB)
    //   cnt    : [nseg] int        (3.2 MB)
    //   bsum   : [1024] int
    //   wb     : [R*128*128] bf16  (0.26 MB)
    char* ws = (char*)d_ws;
    unsigned short* nb = (unsigned short*)ws;
    size_t off = (size_t)N * HFR * sizeof(unsigned short);
    u64* sorted = (u64*)(ws + off);
    off += (size_t)nnz * sizeof(u64);
    int* cnt = (int*)(ws + off);
    off += (size_t)nseg * sizeof(int);
    int* bsum = (int*)(ws + off);
    off += 4096;
    unsigned short* wb = (unsigned short*)(ws + off);

    float* out = (float*)d_out;

    const int nfeat = N * HFR;           // 12.8M
    const int nw    = R * HFR * HTO;     // 131072
    const int ZB = (nseg + 1023) / 1024;             // zero-cnt blocks
    const int CB = (nfeat + 2047) / 2048;            // node-convert blocks
    const int WB = (nw + 2047) / 2048;               // weight-convert blocks
    const int EB = (nnz + 255) / 256;                // edge-parallel blocks
    const int NB = (nseg + 1023) / 1024;             // scan blocks (782 <= 1024)
    const int TB = (N + TM - 1) / TM;                // fused tiles (1563)

    // 1) zero cnt + convert nodes & weights to bf16
    prep_kernel<<<ZB + CB + WB, 256, 0, stream>>>(nodes, weights, cnt, nb, wb,
                                                  nseg, nfeat, nw, ZB, CB);
    // 2) histogram over full row ids
    count_kernel<<<EB, 256, 0, stream>>>(rows, cnt, nnz);
    // 3) exclusive scan
    scan_reduce<<<NB, 256, 0, stream>>>(cnt, bsum, nseg);
    scan_block<<<1, 1024, 0, stream>>>(bsum, NB);
    scan_final<<<NB, 256, 0, stream>>>(cnt, bsum, nseg);
    // 4) bin edges by (r, dst); records carry dst&63
    place_kernel<<<EB, 256, 0, stream>>>(rows, cols, vals, cnt, sorted, N, nnz);
    // 5) fused aggregate + batched GEMM + relu (no global intermediate)
    fused_kernel<<<TB, 256, 0, stream>>>(sorted, cnt, nb, wb, out, N, R);
}

// Round 8
// 419.175 us; speedup vs baseline: 3.6477x; 3.6477x over previous
//
#include <hip/hip_runtime.h>
#include <hip/hip_bf16.h>
#include <stdint.h>

#define HFR 128
#define HTO 128
#define LDN 136   // LDS row stride in bf16 (16B-aligned rows)

typedef short short8 __attribute__((ext_vector_type(8)));   // 8 bf16 = 4 VGPRs
typedef float f32x4  __attribute__((ext_vector_type(4)));   // MFMA C/D
typedef unsigned long long u64;

static __device__ __forceinline__ unsigned short f2bf(float x) {
    __hip_bfloat16 h = __float2bfloat16(x);
    return *reinterpret_cast<unsigned short*>(&h);
}
static __device__ __forceinline__ float bf2f(unsigned short x) {
    return __uint_as_float((unsigned int)x << 16);
}

// ---------------------------------------------------------------------------
// zero cnt[N] (int4 stores; N % 4 == 0)
// ---------------------------------------------------------------------------
__global__ __launch_bounds__(256) void zero_i32(int* __restrict__ p, int n) {
    int i = (blockIdx.x * 256 + threadIdx.x) * 4;
    if (i < n) *reinterpret_cast<int4*>(p + i) = make_int4(0, 0, 0, 0);
}

// ---------------------------------------------------------------------------
// histogram of destination nodes (dst = row mod N)
// ---------------------------------------------------------------------------
__global__ __launch_bounds__(256)
void count_kernel(const int* __restrict__ rows, int* __restrict__ cnt,
                  int N, int nnz) {
    int e = blockIdx.x * 256 + threadIdx.x;
    if (e >= nnz) return;
    int row = rows[e];
    int r   = row / N;
    atomicAdd(&cnt[row - r * N], 1);
}

// ---------------------------------------------------------------------------
// hierarchical exclusive scan, 1024 elems per 256-thread block (int4).
// ---------------------------------------------------------------------------
__global__ __launch_bounds__(256)
void scan_reduce(const int* __restrict__ cnt, int* __restrict__ bsum, int n) {
    __shared__ int s[256];
    int t = threadIdx.x;
    int i = blockIdx.x * 1024 + t * 4;
    int v = 0;
    if (i + 3 < n) { int4 q = *reinterpret_cast<const int4*>(cnt + i); v = q.x + q.y + q.z + q.w; }
    else { for (int k = 0; k < 4; ++k) if (i + k < n) v += cnt[i + k]; }
    s[t] = v;
    __syncthreads();
    for (int off = 128; off > 0; off >>= 1) {
        if (t < off) s[t] += s[t + off];
        __syncthreads();
    }
    if (t == 0) bsum[blockIdx.x] = s[0];
}

__global__ __launch_bounds__(1024)
void scan_block(int* __restrict__ bsum, int nb) {
    __shared__ int s[1024];
    int t = threadIdx.x;
    s[t] = (t < nb) ? bsum[t] : 0;
    __syncthreads();
    for (int off = 1; off < 1024; off <<= 1) {
        int o = (t >= off) ? s[t - off] : 0;
        __syncthreads();
        s[t] += o;
        __syncthreads();
    }
    if (t < nb) bsum[t] = (t == 0) ? 0 : s[t - 1];
}

__global__ __launch_bounds__(256)
void scan_final(int* __restrict__ cnt, const int* __restrict__ bsum, int n) {
    __shared__ int s[256];
    int t = threadIdx.x;
    int i = blockIdx.x * 1024 + t * 4;
    int4 q = make_int4(0, 0, 0, 0);
    if (i + 3 < n) q = *reinterpret_cast<const int4*>(cnt + i);
    else {
        if (i     < n) q.x = cnt[i];
        if (i + 1 < n) q.y = cnt[i + 1];
        if (i + 2 < n) q.z = cnt[i + 2];
    }
    int tot = q.x + q.y + q.z + q.w;
    s[t] = tot;
    __syncthreads();
    for (int off = 1; off < 256; off <<= 1) {
        int o = (t >= off) ? s[t - off] : 0;
        __syncthreads();
        s[t] += o;
        __syncthreads();
    }
    int ex = ((t == 0) ? 0 : s[t - 1]) + bsum[blockIdx.x];
    int4 w;
    w.x = ex; w.y = ex + q.x; w.z = w.y + q.y; w.w = w.z + q.z;
    if (i + 3 < n) *reinterpret_cast<int4*>(cnt + i) = w;
    else {
        if (i     < n) cnt[i]     = w.x;
        if (i + 1 < n) cnt[i + 1] = w.y;
        if (i + 2 < n) cnt[i + 2] = w.z;
    }
}

// ---------------------------------------------------------------------------
// FUSED kernel: blocks [0, Tblocks) = MFMA transform (H[r] = nodes @ W[r]^T,
// bf16 store); blocks [Tblocks, ...) = counting-sort placement by dst.
// Transform epilogue: per r, C fragments -> LDS (bf16, reusing wt region)
// -> coalesced short8 global stores. This removes the 102M scalar 2B stores
// that made round 4's transform issue-bound (150us, both pipes idle).
// C/D layout: col = lane&15, row = quad*4 + reg (verified rounds 3-6).
// ---------------------------------------------------------------------------
__global__ __launch_bounds__(256, 2)
void fused_tp(const float* __restrict__ nodes,
              const float* __restrict__ weights,
              __hip_bfloat16* __restrict__ H,
              const int* __restrict__ rows, const int* __restrict__ cols,
              const float* __restrict__ vals,
              int* __restrict__ cursor, u64* __restrict__ sorted,
              int N, int R, int nnz, int Tblocks) {
    __shared__ unsigned short nd[128 * LDN];
    __shared__ unsigned short wt[128 * LDN];

    if ((int)blockIdx.x >= Tblocks) {
        // ---------------- place: counting-sort pass 2 (key = dst) ----------
        int e = (blockIdx.x - Tblocks) * 256 + threadIdx.x;
        if (e >= nnz) return;
        int row = rows[e];
        int r   = row / N;
        int dst = row - r * N;
        int pos = atomicAdd(&cursor[dst], 1);
        unsigned int lo = (unsigned int)cols[e] | ((unsigned int)r << 17);
        sorted[pos] = ((u64)__float_as_uint(vals[e]) << 32) | (u64)lo;
        return;
    }

    // ---------------- transform ----------------
    const int t    = threadIdx.x;
    const int n0   = blockIdx.x * 128;
    const int lane = t & 63;
    const int w    = t >> 6;
    const int m    = lane & 15;
    const int quad = lane >> 4;
    const int q8   = quad * 8;
    const int w32  = w * 32;

    // stage node tile fp32 -> bf16
    const float4* src4 = reinterpret_cast<const float4*>(nodes);
#pragma unroll
    for (int it = 0; it < 8; ++it) {
        int id  = t + 256 * it;
        int row = id >> 4;
        int k8  = id & 15;
        float4 v0 = make_float4(0.f, 0.f, 0.f, 0.f);
        float4 v1 = v0;
        if (n0 + row < N) {
            v0 = src4[(size_t)(n0 + row) * 32 + k8 * 2];
            v1 = src4[(size_t)(n0 + row) * 32 + k8 * 2 + 1];
        }
        short8 sv;
        sv[0] = f2bf(v0.x); sv[1] = f2bf(v0.y); sv[2] = f2bf(v0.z); sv[3] = f2bf(v0.w);
        sv[4] = f2bf(v1.x); sv[5] = f2bf(v1.y); sv[6] = f2bf(v1.z); sv[7] = f2bf(v1.w);
        *reinterpret_cast<short8*>(&nd[row * LDN + k8 * 8]) = sv;
    }

    for (int r = 0; r < R; ++r) {
        __syncthreads();   // prev r's epilogue readers of wt done
        // stage W[r] fp32 -> bf16
        const float4* wsrc = reinterpret_cast<const float4*>(weights + (size_t)r * HFR * HTO);
#pragma unroll
        for (int it = 0; it < 8; ++it) {
            int id  = t + 256 * it;
            int row = id >> 4;
            int k8  = id & 15;
            float4 v0 = wsrc[row * 32 + k8 * 2];
            float4 v1 = wsrc[row * 32 + k8 * 2 + 1];
            short8 sv;
            sv[0] = f2bf(v0.x); sv[1] = f2bf(v0.y); sv[2] = f2bf(v0.z); sv[3] = f2bf(v0.w);
            sv[4] = f2bf(v1.x); sv[5] = f2bf(v1.y); sv[6] = f2bf(v1.z); sv[7] = f2bf(v1.w);
            *reinterpret_cast<short8*>(&wt[row * LDN + k8 * 8]) = sv;
        }
        __syncthreads();

        f32x4 acc[2][8];
#pragma unroll
        for (int t2 = 0; t2 < 2; ++t2)
#pragma unroll
            for (int j = 0; j < 8; ++j) acc[t2][j] = (f32x4)(0.f);

#pragma unroll
        for (int kk = 0; kk < HFR; kk += 32) {
            short8 a0 = *reinterpret_cast<const short8*>(&nd[(w32 +      m) * LDN + kk + q8]);
            short8 a1 = *reinterpret_cast<const short8*>(&nd[(w32 + 16 + m) * LDN + kk + q8]);
#pragma unroll
            for (int j = 0; j < 8; ++j) {
                short8 b = *reinterpret_cast<const short8*>(&wt[(j * 16 + m) * LDN + kk + q8]);
                acc[0][j] = __builtin_amdgcn_mfma_f32_16x16x32_bf16(a0, b, acc[0][j], 0, 0, 0);
                acc[1][j] = __builtin_amdgcn_mfma_f32_16x16x32_bf16(a1, b, acc[1][j], 0, 0, 0);
            }
        }

        // ---- epilogue: C -> LDS (bf16, overwrite wt) -> coalesced H stores
        __syncthreads();   // all waves done reading wt B-fragments
#pragma unroll
        for (int t2 = 0; t2 < 2; ++t2) {
            int rowb = w32 + t2 * 16 + quad * 4;
#pragma unroll
            for (int reg = 0; reg < 4; ++reg)
#pragma unroll
                for (int j = 0; j < 8; ++j)
                    wt[(rowb + reg) * LDN + 16 * j + m] = f2bf(acc[t2][j][reg]);
        }
        __syncthreads();
        __hip_bfloat16* hdst = H + (size_t)r * N * HTO;
#pragma unroll
        for (int it = 0; it < 8; ++it) {
            int id  = t + 256 * it;        // 128 rows x 16 short8-chunks
            int row = id >> 4;
            int k8  = id & 15;
            if (n0 + row < N)
                *reinterpret_cast<short8*>(
                    reinterpret_cast<unsigned short*>(hdst) +
                    ((size_t)(n0 + row) << 7) + k8 * 8) =
                    *reinterpret_cast<const short8*>(&wt[row * LDN + k8 * 8]);
        }
    }
}

// ---------------------------------------------------------------------------
// pull-gather: TWO waves per dst node, each owning a 64-feature half
// (128B contiguous per edge -> 2x outstanding requests vs full-row waves).
// Records batch-loaded via scalar cache (readfirstlane). No atomics; single
// relu'd coalesced store per (node, half).
// ---------------------------------------------------------------------------
__global__ __launch_bounds__(256)
void gather_kernel(const u64* __restrict__ sorted,
                   const int* __restrict__ cnt,
                   const unsigned short* __restrict__ Hu,
                   float* __restrict__ out, int N) {
    const int gw   = blockIdx.x * 4 + (threadIdx.x >> 6);
    const int lane = threadIdx.x & 63;
    const int n    = gw >> 1;
    const int half = gw & 1;
    if (n >= N) return;

    int e         = (n == 0) ? 0 : cnt[n - 1];
    const int end = cnt[n];
    const int fo  = half * 64 + lane;   // feature offset 0..127

    float a0 = 0.f, b0 = 0.f, c0 = 0.f, d0 = 0.f;

#define HIDX(q) (((((size_t)(((unsigned int)(q) >> 17) & 7)) * (size_t)N + \
                   (size_t)((unsigned int)(q) & 0x1FFFF)) << 7) + fo)
#define VALF(q) __uint_as_float((unsigned int)((q) >> 32))

    for (; e + 8 <= end; e += 8) {
        const u64* p = sorted + __builtin_amdgcn_readfirstlane(e);
        u64 q0 = p[0], q1 = p[1], q2 = p[2], q3 = p[3];
        u64 q4 = p[4], q5 = p[5], q6 = p[6], q7 = p[7];
        unsigned short x0 = Hu[HIDX(q0)];
        unsigned short x1 = Hu[HIDX(q1)];
        unsigned short x2 = Hu[HIDX(q2)];
        unsigned short x3 = Hu[HIDX(q3)];
        unsigned short x4 = Hu[HIDX(q4)];
        unsigned short x5 = Hu[HIDX(q5)];
        unsigned short x6 = Hu[HIDX(q6)];
        unsigned short x7 = Hu[HIDX(q7)];
        a0 = fmaf(bf2f(x0), VALF(q0), a0);
        b0 = fmaf(bf2f(x1), VALF(q1), b0);
        c0 = fmaf(bf2f(x2), VALF(q2), c0);
        d0 = fmaf(bf2f(x3), VALF(q3), d0);
        a0 = fmaf(bf2f(x4), VALF(q4), a0);
        b0 = fmaf(bf2f(x5), VALF(q5), b0);
        c0 = fmaf(bf2f(x6), VALF(q6), c0);
        d0 = fmaf(bf2f(x7), VALF(q7), d0);
    }
    for (; e + 2 <= end; e += 2) {
        const u64* p = sorted + __builtin_amdgcn_readfirstlane(e);
        u64 q0 = p[0], q1 = p[1];
        unsigned short x0 = Hu[HIDX(q0)];
        unsigned short x1 = Hu[HIDX(q1)];
        a0 = fmaf(bf2f(x0), VALF(q0), a0);
        b0 = fmaf(bf2f(x1), VALF(q1), b0);
    }
    if (e < end) {
        u64 q0 = sorted[e];
        unsigned short x0 = Hu[HIDX(q0)];
        a0 = fmaf(bf2f(x0), VALF(q0), a0);
    }
#undef HIDX
#undef VALF

    out[(size_t)n * HTO + fo] = fmaxf(a0 + b0 + c0 + d0, 0.f);
}

// ---------------------------------------------------------------------------
extern "C" void kernel_launch(void* const* d_in, const int* in_sizes, int n_in,
                              void* d_out, int out_size, void* d_ws, size_t ws_size,
                              hipStream_t stream) {
    const float* nodes   = (const float*)d_in[0];   // [N, HFR] fp32
    const int*   indices = (const int*)d_in[1];     // [2, NNZ] int32
    const float* vals    = (const float*)d_in[2];   // [NNZ] fp32
    const float* weights = (const float*)d_in[3];   // [R, HFR, HTO] fp32

    const int N   = in_sizes[0] / HFR;
    const int nnz = in_sizes[1] / 2;
    const int R   = in_sizes[3] / (HFR * HTO);

    const int* rows = indices;
    const int* cols = indices + nnz;

    // ws layout (~218 MB, proven in rounds 3-4):
    //   H      : [R, N, HTO] bf16   (204.8 MB)
    //   sorted : [nnz] u64          (12.8 MB)
    //   cnt    : [N] int            (0.4 MB)   histogram -> cursor -> seg-ends
    //   bsum   : [1024] int
    char* ws = (char*)d_ws;
    __hip_bfloat16* H = (__hip_bfloat16*)ws;
    size_t off = (size_t)R * N * HTO * sizeof(__hip_bfloat16);
    u64* sorted = (u64*)(ws + off);
    off += (size_t)nnz * sizeof(u64);
    int* cnt = (int*)(ws + off);
    off += (size_t)N * sizeof(int);
    int* bsum = (int*)(ws + off);

    float* out = (float*)d_out;

    const int NB      = (N + 1023) / 1024;     // 98 scan/zero blocks
    const int EB      = (nnz + 255) / 256;     // 6250 edge blocks
    const int Tblocks = (N + 127) / 128;       // 782 transform tiles

    // 1) zero histogram
    zero_i32<<<NB, 256, 0, stream>>>(cnt, N);
    // 2) degree histogram (dst-keyed)
    count_kernel<<<EB, 256, 0, stream>>>(rows, cnt, N, nnz);
    // 3) exclusive scan
    scan_reduce<<<NB, 256, 0, stream>>>(cnt, bsum, N);
    scan_block<<<1, 1024, 0, stream>>>(bsum, NB);
    scan_final<<<NB, 256, 0, stream>>>(cnt, bsum, N);
    // 4) transform (MFMA, coalesced H epilogue) || counting-sort placement
    fused_tp<<<Tblocks + EB, 256, 0, stream>>>(nodes, weights, H,
                                               rows, cols, vals,
                                               cnt, sorted, N, R, nnz, Tblocks);
    // 5) pull-gather + relu (2 waves per node)
    gather_kernel<<<(2 * N + 3) / 4, 256, 0, stream>>>(
        sorted, cnt, (const unsigned short*)H, out, N);
}